// Round 1
// baseline (732.995 us; speedup 1.0000x reference)
//
#include <hip/hip_runtime.h>
#include <hip/hip_bf16.h>

typedef __attribute__((ext_vector_type(4))) float  f32x4;
typedef __attribute__((ext_vector_type(8))) short  bf16x8;
typedef __attribute__((ext_vector_type(4))) short  bf16x4v;

#define BM 128
#define BN 128
#define BK 32
#define PADK 40   // bf16 elems per LDS row (80 B, multiple of 16 B for ds_read_b128)

__device__ __forceinline__ unsigned short f2bf(float f) {
  __hip_bfloat16 h = __float2bfloat16(f);
  unsigned short u; __builtin_memcpy(&u, &h, 2); return u;
}

// ---- kernel 1: W (H,H) f32 row-major -> Wt (H,H) bf16, transposed (Wt[n][k] = W[k][n]) ----
__global__ __launch_bounds__(256)
void transpose_W(const float* __restrict__ W, unsigned short* __restrict__ Wt, int H) {
  __shared__ float tile[64][65];
  const int k0 = blockIdx.y * 64;
  const int n0 = blockIdx.x * 64;
  const int t = threadIdx.x;
  #pragma unroll
  for (int it = 0; it < 4; ++it) {
    int q = it * 256 + t;
    int r = q >> 4, c4 = (q & 15) << 2;
    f32x4 v = *(const f32x4*)&W[(size_t)(k0 + r) * H + n0 + c4];
    tile[r][c4 + 0] = v[0]; tile[r][c4 + 1] = v[1];
    tile[r][c4 + 2] = v[2]; tile[r][c4 + 3] = v[3];
  }
  __syncthreads();
  #pragma unroll
  for (int it = 0; it < 4; ++it) {
    int q = it * 256 + t;
    int r = q >> 4, c4 = (q & 15) << 2;   // r = n-index of Wt tile, c4 = k-offset
    bf16x4v o;
    #pragma unroll
    for (int j = 0; j < 4; ++j) o[j] = (short)f2bf(tile[c4 + j][r]);
    *(bf16x4v*)&Wt[(size_t)(n0 + r) * H + k0 + c4] = o;
  }
}

// ---- kernel 2: fused bf16-MFMA GEMM + trig terms + ODE scalar scale ----
__global__ __launch_bounds__(256, 2)
void gemm_fused(const float* __restrict__ x, const unsigned short* __restrict__ Wt,
                const float* __restrict__ bv, const float* __restrict__ cv,
                const float* __restrict__ dv, float* __restrict__ out,
                float S, int H) {
  __shared__ unsigned short As[BM * PADK];
  __shared__ unsigned short Bs[BN * PADK];

  const int tid  = threadIdx.x;
  const int bj   = blockIdx.x;       // N tile index (8)  -- fast dim: W panel reuse
  const int bi   = blockIdx.y;       // M tile index (128)
  const int i0   = bi * BM, j0 = bj * BN;
  const int wave = tid >> 6, lane = tid & 63;
  const int wr = wave >> 1, wc = wave & 1;   // 2x2 waves, each owns 64x64 of C
  const int l16 = lane & 15, lq = lane >> 4;

  f32x4 acc[4][4] = {};   // acc[mi][ni] : 16x16 fragments

  for (int kk = 0; kk < H; kk += BK) {
    // stage A tile: x[i0..i0+128][kk..kk+32]  f32 -> bf16 into LDS
    #pragma unroll
    for (int it = 0; it < 4; ++it) {
      int q = it * 256 + tid;            // 0..1023, 4 floats each
      int r = q >> 3, k4 = (q & 7) << 2;
      f32x4 v = *(const f32x4*)&x[(size_t)(i0 + r) * H + kk + k4];
      bf16x4v o;
      #pragma unroll
      for (int j = 0; j < 4; ++j) o[j] = (short)f2bf(v[j]);
      *(bf16x4v*)&As[r * PADK + k4] = o;
    }
    // stage B tile: Wt[j0..j0+128][kk..kk+32]  bf16 copy into LDS
    #pragma unroll
    for (int it = 0; it < 2; ++it) {
      int q = it * 256 + tid;            // 0..511, 8 bf16 each
      int r = q >> 2, k8 = (q & 3) << 3;
      bf16x8 v = *(const bf16x8*)&Wt[(size_t)(j0 + r) * H + kk + k8];
      *(bf16x8*)&Bs[r * PADK + k8] = v;
    }
    __syncthreads();

    bf16x8 af[4], bfr[4];
    #pragma unroll
    for (int mi = 0; mi < 4; ++mi)
      af[mi] = *(const bf16x8*)&As[(wr * 64 + mi * 16 + l16) * PADK + lq * 8];
    #pragma unroll
    for (int ni = 0; ni < 4; ++ni)
      bfr[ni] = *(const bf16x8*)&Bs[(wc * 64 + ni * 16 + l16) * PADK + lq * 8];

    #pragma unroll
    for (int mi = 0; mi < 4; ++mi)
      #pragma unroll
      for (int ni = 0; ni < 4; ++ni)
        acc[mi][ni] = __builtin_amdgcn_mfma_f32_16x16x32_bf16(af[mi], bfr[ni], acc[mi][ni], 0, 0, 0);
    __syncthreads();
  }

  // epilogue: z = acc + b*sin(x) + c*cos(x) + d*tan(x);  out = S*z
  // C/D layout: col = lane&15, row = (lane>>4)*4 + reg   [m89-verified]
  #pragma unroll
  for (int ni = 0; ni < 4; ++ni) {
    const int j = j0 + wc * 64 + ni * 16 + l16;
    const float bj_ = bv[j], cj_ = cv[j], dj_ = dv[j];
    #pragma unroll
    for (int mi = 0; mi < 4; ++mi) {
      const int ib = i0 + wr * 64 + mi * 16 + lq * 4;
      #pragma unroll
      for (int r = 0; r < 4; ++r) {
        const int i = ib + r;
        const float xv = x[(size_t)i * H + j];
        float s, co;
        sincosf(xv, &s, &co);                  // precise versions (tan near pole!)
        const float z = acc[mi][ni][r] + bj_ * s + cj_ * co + dj_ * (s / co);
        out[(size_t)i * H + j] = S * z;
      }
    }
  }
}

extern "C" void kernel_launch(void* const* d_in, const int* in_sizes, int n_in,
                              void* d_out, int out_size, void* d_ws, size_t ws_size,
                              hipStream_t stream) {
  const float* x = (const float*)d_in[0];
  const float* W = (const float*)d_in[1];
  const float* b = (const float*)d_in[2];
  const float* c = (const float*)d_in[3];
  const float* d = (const float*)d_in[4];
  float* out = (float*)d_out;
  const int H = in_sizes[2];          // 1024
  const int M = in_sizes[0] / H;      // 16384

  // Scalar RK4 factor: y_final = S * z (ODE linear in y, y0 = 0).
  // Emulate jnp.linspace(0,1,100) in f32, recurrence in double (2% tolerance -> negligible).
  const int NT = 100;
  float ts[NT];
  const float step = (float)(1.0 / 99.0);
  for (int i = 0; i < NT; ++i) ts[i] = (float)i * step;
  ts[NT - 1] = 1.0f;
  double yy = 0.0;
  for (int i = 0; i < NT - 1; ++i) {
    const double t = (double)ts[i], dt = (double)(ts[i + 1] - ts[i]);
    const double k1 = t - yy;
    const double k2 = (t + 0.5 * dt) - (yy + 0.5 * dt * k1);
    const double k3 = (t + 0.5 * dt) - (yy + 0.5 * dt * k2);
    const double k4 = (t + dt) - (yy + dt * k3);
    yy += dt / 6.0 * (k1 + 2.0 * k2 + 2.0 * k3 + k4);
  }
  const float S = (float)yy;

  unsigned short* Wt = (unsigned short*)d_ws;   // 2 MB bf16 W^T
  dim3 tgrid(H / 64, H / 64);
  transpose_W<<<tgrid, 256, 0, stream>>>(W, Wt, H);

  dim3 ggrid(H / BN, M / BM);    // x-fast over N tiles -> W panel L2 reuse
  gemm_fused<<<ggrid, 256, 0, stream>>>(x, Wt, b, c, d, out, S, H);
}

// Round 2
// 641.823 us; speedup vs baseline: 1.1421x; 1.1421x over previous
//
#include <hip/hip_runtime.h>
#include <hip/hip_bf16.h>

typedef __attribute__((ext_vector_type(4))) float  f32x4;
typedef __attribute__((ext_vector_type(8))) short  bf16x8;
typedef __attribute__((ext_vector_type(4))) short  bf16x4v;

#define BM 128
#define BN 128
#define BK 32
#define PADK 40   // bf16 elems per LDS row (80 B, multiple of 16 B for ds_read_b128)
#define EPAD 68   // f32 elems per epilogue LDS row (64 + 4 pad)

__device__ __forceinline__ unsigned short f2bf(float f) {
  __hip_bfloat16 h = __float2bfloat16(f);
  unsigned short u; __builtin_memcpy(&u, &h, 2); return u;
}

// ---- kernel 1: W (H,H) f32 row-major -> Wt (H,H) bf16, transposed (Wt[n][k] = W[k][n]) ----
__global__ __launch_bounds__(256)
void transpose_W(const float* __restrict__ W, unsigned short* __restrict__ Wt, int H) {
  __shared__ float tile[64][65];
  const int k0 = blockIdx.y * 64;
  const int n0 = blockIdx.x * 64;
  const int t = threadIdx.x;
  #pragma unroll
  for (int it = 0; it < 4; ++it) {
    int q = it * 256 + t;
    int r = q >> 4, c4 = (q & 15) << 2;
    f32x4 v = *(const f32x4*)&W[(size_t)(k0 + r) * H + n0 + c4];
    tile[r][c4 + 0] = v[0]; tile[r][c4 + 1] = v[1];
    tile[r][c4 + 2] = v[2]; tile[r][c4 + 3] = v[3];
  }
  __syncthreads();
  #pragma unroll
  for (int it = 0; it < 4; ++it) {
    int q = it * 256 + t;
    int r = q >> 4, c4 = (q & 15) << 2;   // r = n-index of Wt tile, c4 = k-offset
    bf16x4v o;
    #pragma unroll
    for (int j = 0; j < 4; ++j) o[j] = (short)f2bf(tile[c4 + j][r]);
    *(bf16x4v*)&Wt[(size_t)(n0 + r) * H + k0 + c4] = o;
  }
}

// ---- kernel 2: fused bf16-MFMA GEMM + trig terms + ODE scalar scale ----
__global__ __launch_bounds__(256, 2)
void gemm_fused(const float* __restrict__ x, const unsigned short* __restrict__ Wt,
                const float* __restrict__ bv, const float* __restrict__ cv,
                const float* __restrict__ dv, float* __restrict__ out,
                float S, int H) {
  __shared__ unsigned short As[BM * PADK];
  __shared__ unsigned short Bs[BN * PADK];
  __shared__ float Es[4][16 * EPAD];      // per-wave epilogue transpose tile

  const int tid  = threadIdx.x;
  const int bj   = blockIdx.x;       // N tile index (8)  -- fast dim: W panel reuse
  const int bi   = blockIdx.y;       // M tile index (128)
  const int i0   = bi * BM, j0 = bj * BN;
  const int wave = tid >> 6, lane = tid & 63;
  const int wr = wave >> 1, wc = wave & 1;   // 2x2 waves, each owns 64x64 of C
  const int l16 = lane & 15, lq = lane >> 4;

  f32x4 acc[4][4] = {};   // acc[mi][ni] : 16x16 fragments

  for (int kk = 0; kk < H; kk += BK) {
    // stage A tile: x[i0..i0+128][kk..kk+32]  f32 -> bf16 into LDS
    #pragma unroll
    for (int it = 0; it < 4; ++it) {
      int q = it * 256 + tid;            // 0..1023, 4 floats each
      int r = q >> 3, k4 = (q & 7) << 2;
      f32x4 v = *(const f32x4*)&x[(size_t)(i0 + r) * H + kk + k4];
      bf16x4v o;
      #pragma unroll
      for (int j = 0; j < 4; ++j) o[j] = (short)f2bf(v[j]);
      *(bf16x4v*)&As[r * PADK + k4] = o;
    }
    // stage B tile: Wt[j0..j0+128][kk..kk+32]  bf16 copy into LDS
    #pragma unroll
    for (int it = 0; it < 2; ++it) {
      int q = it * 256 + tid;            // 0..511, 8 bf16 each
      int r = q >> 2, k8 = (q & 3) << 3;
      bf16x8 v = *(const bf16x8*)&Wt[(size_t)(j0 + r) * H + kk + k8];
      *(bf16x8*)&Bs[r * PADK + k8] = v;
    }
    __syncthreads();

    bf16x8 af[4], bfr[4];
    #pragma unroll
    for (int mi = 0; mi < 4; ++mi)
      af[mi] = *(const bf16x8*)&As[(wr * 64 + mi * 16 + l16) * PADK + lq * 8];
    #pragma unroll
    for (int ni = 0; ni < 4; ++ni)
      bfr[ni] = *(const bf16x8*)&Bs[(wc * 64 + ni * 16 + l16) * PADK + lq * 8];

    #pragma unroll
    for (int mi = 0; mi < 4; ++mi)
      #pragma unroll
      for (int ni = 0; ni < 4; ++ni)
        acc[mi][ni] = __builtin_amdgcn_mfma_f32_16x16x32_bf16(af[mi], bfr[ni], acc[mi][ni], 0, 0, 0);
    __syncthreads();
  }

  // ---- epilogue: per-wave LDS transpose of the C fragments, then fully
  // coalesced f32x4 read of x + trig + f32x4 store of out. ----
  // C/D fragment layout: col = l16, row = lq*4 + r  [m89-verified]
  float* ep = Es[wave];
  const int rr = lane >> 2;           // 0..15 : row within 16-row stripe
  const int cq = (lane & 3) * 16;     // 0,16,32,48 : col quarter
  #pragma unroll
  for (int mi = 0; mi < 4; ++mi) {
    // stage: fragment layout -> LDS (2 lanes/bank max: free)
    #pragma unroll
    for (int ni = 0; ni < 4; ++ni)
      #pragma unroll
      for (int r = 0; r < 4; ++r)
        ep[(lq * 4 + r) * EPAD + ni * 16 + l16] = acc[mi][ni][r];
    // same-wave ds_write -> ds_read: LDS pipe is in-order per wave; compiler
    // inserts the lgkmcnt wait (same array, may-alias). No barrier needed.
    const int i  = i0 + wr * 64 + mi * 16 + rr;
    const int jb = j0 + wc * 64 + cq;
    const float* xrow = &x[(size_t)i * H + jb];
    float*       orow = &out[(size_t)i * H + jb];
    #pragma unroll
    for (int t = 0; t < 4; ++t) {
      f32x4 a  = *(const f32x4*)&ep[rr * EPAD + cq + 4 * t];
      f32x4 xv = *(const f32x4*)&xrow[4 * t];
      f32x4 b4 = *(const f32x4*)&bv[jb + 4 * t];
      f32x4 c4 = *(const f32x4*)&cv[jb + 4 * t];
      f32x4 d4 = *(const f32x4*)&dv[jb + 4 * t];
      f32x4 o;
      #pragma unroll
      for (int e = 0; e < 4; ++e) {
        float s, co;
        sincosf(xv[e], &s, &co);            // precise (tan near pole!)
        o[e] = S * (a[e] + b4[e] * s + c4[e] * co + d4[e] * (s / co));
      }
      *(f32x4*)&orow[4 * t] = o;
    }
  }
}

extern "C" void kernel_launch(void* const* d_in, const int* in_sizes, int n_in,
                              void* d_out, int out_size, void* d_ws, size_t ws_size,
                              hipStream_t stream) {
  const float* x = (const float*)d_in[0];
  const float* W = (const float*)d_in[1];
  const float* b = (const float*)d_in[2];
  const float* c = (const float*)d_in[3];
  const float* d = (const float*)d_in[4];
  float* out = (float*)d_out;
  const int H = in_sizes[2];          // 1024
  const int M = in_sizes[0] / H;      // 16384

  // Scalar RK4 factor: y_final = S * z (ODE linear in y, y0 = 0).
  const int NT = 100;
  float ts[NT];
  const float step = (float)(1.0 / 99.0);
  for (int i = 0; i < NT; ++i) ts[i] = (float)i * step;
  ts[NT - 1] = 1.0f;
  double yy = 0.0;
  for (int i = 0; i < NT - 1; ++i) {
    const double t = (double)ts[i], dt = (double)(ts[i + 1] - ts[i]);
    const double k1 = t - yy;
    const double k2 = (t + 0.5 * dt) - (yy + 0.5 * dt * k1);
    const double k3 = (t + 0.5 * dt) - (yy + 0.5 * dt * k2);
    const double k4 = (t + dt) - (yy + dt * k3);
    yy += dt / 6.0 * (k1 + 2.0 * k2 + 2.0 * k3 + k4);
  }
  const float S = (float)yy;

  unsigned short* Wt = (unsigned short*)d_ws;   // 2 MB bf16 W^T
  dim3 tgrid(H / 64, H / 64);
  transpose_W<<<tgrid, 256, 0, stream>>>(W, Wt, H);

  dim3 ggrid(H / BN, M / BM);    // x-fast over N tiles -> W panel L2 reuse
  gemm_fused<<<ggrid, 256, 0, stream>>>(x, Wt, b, c, d, out, S, H);
}

// Round 3
// 101.080 us; speedup vs baseline: 7.2517x; 6.3497x over previous
//
#include <hip/hip_runtime.h>
#include <hip/hip_bf16.h>

typedef __attribute__((ext_vector_type(4))) float  f32x4;
typedef __attribute__((ext_vector_type(8))) short  bf16x8;
typedef __attribute__((ext_vector_type(4))) short  bf16x4v;

#define BM 128
#define BN 128
#define BK 32
#define PADK 40   // bf16 elems per LDS row (80 B, multiple of 16 B for ds_read_b128)
#define EPAD 68   // f32 elems per epilogue LDS row (64 + 4 pad)

__device__ __forceinline__ unsigned short f2bf(float f) {
  __hip_bfloat16 h = __float2bfloat16(f);
  unsigned short u; __builtin_memcpy(&u, &h, 2); return u;
}

// Fully-inline sincos: f64 Cody-Waite reduction (|x| small: x ~ N(0,1)),
// musl-style f32 kernels. No library call -> no call-ABI spills, no scratch.
// Odd/even structure keeps RELATIVE accuracy where |cos| -> 0 (tan pole).
__device__ __forceinline__ void my_sincos(float xf, float& s_out, float& c_out) {
  const double xd = (double)xf;
  const double kd = __builtin_rint(xd * 0.636619772367581343076);   // x * 2/pi
  const int    q  = (int)kd;
  double rd = __builtin_fma(-kd, 1.5707963267948966,    xd);        // pio2_hi (f64)
  rd        = __builtin_fma(-kd, 6.123233995736766e-17, rd);        // pio2_lo
  const float r = (float)rd;
  const float z = r * r;
  const float ps = fmaf(z, fmaf(z, fmaf(z, 2.7183114939898219e-06f,
                                           -1.9839334836096632e-04f),
                                   8.3333293858894632e-03f),
                        -1.6666666641626524e-01f);
  const float sr = fmaf(r * z, ps, r);                              // sin(r)
  const float pc = fmaf(z, fmaf(z, fmaf(z, 2.4390448796277409e-05f,
                                           -1.3886763774609929e-03f),
                                   4.1666623323739063e-02f),
                        -4.9999999725103100e-01f);
  const float cr = fmaf(z, pc, 1.0f);                               // cos(r)
  const bool swap = (q & 1) != 0;
  float s1 = swap ? cr : sr;
  float c1 = swap ? sr : cr;
  if (q & 2)       s1 = -s1;
  if ((q + 1) & 2) c1 = -c1;
  s_out = s1; c_out = c1;
}

// ---- kernel 1: W (H,H) f32 row-major -> Wt (H,H) bf16, transposed ----
__global__ __launch_bounds__(256)
void transpose_W(const float* __restrict__ W, unsigned short* __restrict__ Wt, int H) {
  __shared__ float tile[64][65];
  const int k0 = blockIdx.y * 64;
  const int n0 = blockIdx.x * 64;
  const int t = threadIdx.x;
  #pragma unroll
  for (int it = 0; it < 4; ++it) {
    int q = it * 256 + t;
    int r = q >> 4, c4 = (q & 15) << 2;
    f32x4 v = *(const f32x4*)&W[(size_t)(k0 + r) * H + n0 + c4];
    tile[r][c4 + 0] = v[0]; tile[r][c4 + 1] = v[1];
    tile[r][c4 + 2] = v[2]; tile[r][c4 + 3] = v[3];
  }
  __syncthreads();
  #pragma unroll
  for (int it = 0; it < 4; ++it) {
    int q = it * 256 + t;
    int r = q >> 4, c4 = (q & 15) << 2;
    bf16x4v o;
    #pragma unroll
    for (int j = 0; j < 4; ++j) o[j] = (short)f2bf(tile[c4 + j][r]);
    *(bf16x4v*)&Wt[(size_t)(n0 + r) * H + k0 + c4] = o;
  }
}

// ---- kernel 1b: x f32 -> bf16 (removes 2x staging bytes + per-K convert VALU) ----
__global__ __launch_bounds__(256)
void cvt_x(const float* __restrict__ x, unsigned short* __restrict__ xb, int n4) {
  int i = blockIdx.x * 256 + threadIdx.x;
  const int stride = gridDim.x * 256;
  for (; i < n4; i += stride) {
    f32x4 v = ((const f32x4*)x)[i];
    bf16x4v o;
    #pragma unroll
    for (int j = 0; j < 4; ++j) o[j] = (short)f2bf(v[j]);
    ((bf16x4v*)xb)[i] = o;
  }
}

// ---- kernel 2: fused bf16-MFMA GEMM + inline trig epilogue + ODE scale ----
template <bool XB>
__global__ __launch_bounds__(256, 2)
void gemm_fused(const float* __restrict__ x, const unsigned short* __restrict__ xb,
                const unsigned short* __restrict__ Wt,
                const float* __restrict__ bv, const float* __restrict__ cv,
                const float* __restrict__ dv, float* __restrict__ out,
                float S, int H) {
  // As/Bs (K-loop lifetime) and Es (epilogue lifetime) share one allocation.
  __shared__ unsigned char smem[BM * PADK * 2 + BN * PADK * 2];   // 20480 B >= Es 17408 B
  unsigned short* As = (unsigned short*)smem;
  unsigned short* Bs = As + BM * PADK;
  float*          Es = (float*)smem;

  const int tid  = threadIdx.x;
  const int bj   = blockIdx.x;       // N tile (8) -- fast dim
  const int bi   = blockIdx.y;       // M tile (128)
  const int i0   = bi * BM, j0 = bj * BN;
  const int wave = tid >> 6, lane = tid & 63;
  const int wr = wave >> 1, wc = wave & 1;
  const int l16 = lane & 15, lq = lane >> 4;

  f32x4 acc[4][4] = {};

  for (int kk = 0; kk < H; kk += BK) {
    if (XB) {
      // stage A from bf16 x: straight bf16x8 copy
      #pragma unroll
      for (int it = 0; it < 2; ++it) {
        int q = it * 256 + tid;            // 0..511, 8 bf16 each
        int r = q >> 2, k8 = (q & 3) << 3;
        bf16x8 v = *(const bf16x8*)&xb[(size_t)(i0 + r) * H + kk + k8];
        *(bf16x8*)&As[r * PADK + k8] = v;
      }
    } else {
      // stage A from f32 x with convert
      #pragma unroll
      for (int it = 0; it < 4; ++it) {
        int q = it * 256 + tid;            // 0..1023, 4 floats each
        int r = q >> 3, k4 = (q & 7) << 2;
        f32x4 v = *(const f32x4*)&x[(size_t)(i0 + r) * H + kk + k4];
        bf16x4v o;
        #pragma unroll
        for (int j = 0; j < 4; ++j) o[j] = (short)f2bf(v[j]);
        *(bf16x4v*)&As[r * PADK + k4] = o;
      }
    }
    // stage B from bf16 Wt
    #pragma unroll
    for (int it = 0; it < 2; ++it) {
      int q = it * 256 + tid;              // 0..511, 8 bf16 each
      int r = q >> 2, k8 = (q & 3) << 3;
      bf16x8 v = *(const bf16x8*)&Wt[(size_t)(j0 + r) * H + kk + k8];
      *(bf16x8*)&Bs[r * PADK + k8] = v;
    }
    __syncthreads();

    bf16x8 af[4], bfr[4];
    #pragma unroll
    for (int mi = 0; mi < 4; ++mi)
      af[mi] = *(const bf16x8*)&As[(wr * 64 + mi * 16 + l16) * PADK + lq * 8];
    #pragma unroll
    for (int ni = 0; ni < 4; ++ni)
      bfr[ni] = *(const bf16x8*)&Bs[(wc * 64 + ni * 16 + l16) * PADK + lq * 8];

    #pragma unroll
    for (int mi = 0; mi < 4; ++mi)
      #pragma unroll
      for (int ni = 0; ni < 4; ++ni)
        acc[mi][ni] = __builtin_amdgcn_mfma_f32_16x16x32_bf16(af[mi], bfr[ni], acc[mi][ni], 0, 0, 0);
    __syncthreads();   // also makes As/Bs dead before Es reuse below
  }

  // ---- epilogue: per-wave LDS transpose, coalesced f32x4 IO, inline trig ----
  // C/D fragment layout: col = l16, row = lq*4 + r  [m89-verified]
  float* ep = Es + wave * (16 * EPAD);
  const int rr = lane >> 2;           // 0..15
  const int cq = (lane & 3) * 16;     // 0,16,32,48
  #pragma unroll
  for (int mi = 0; mi < 4; ++mi) {
    #pragma unroll
    for (int ni = 0; ni < 4; ++ni)
      #pragma unroll
      for (int r = 0; r < 4; ++r)
        ep[(lq * 4 + r) * EPAD + ni * 16 + l16] = acc[mi][ni][r];
    // same-wave ds_write -> ds_read: in-order LDS pipe, compiler waits lgkmcnt.
    const int i  = i0 + wr * 64 + mi * 16 + rr;
    const int jb = j0 + wc * 64 + cq;
    const float* xrow = &x[(size_t)i * H + jb];
    float*       orow = &out[(size_t)i * H + jb];
    #pragma unroll
    for (int t = 0; t < 4; ++t) {
      f32x4 a  = *(const f32x4*)&ep[rr * EPAD + cq + 4 * t];
      f32x4 xv = *(const f32x4*)&xrow[4 * t];
      f32x4 b4 = *(const f32x4*)&bv[jb + 4 * t];
      f32x4 c4 = *(const f32x4*)&cv[jb + 4 * t];
      f32x4 d4 = *(const f32x4*)&dv[jb + 4 * t];
      f32x4 o;
      #pragma unroll
      for (int e = 0; e < 4; ++e) {
        float s, co;
        my_sincos(xv[e], s, co);
        o[e] = S * (a[e] + b4[e] * s + c4[e] * co + d4[e] * (s / co));
      }
      *(f32x4*)&orow[4 * t] = o;
    }
  }
}

extern "C" void kernel_launch(void* const* d_in, const int* in_sizes, int n_in,
                              void* d_out, int out_size, void* d_ws, size_t ws_size,
                              hipStream_t stream) {
  const float* x = (const float*)d_in[0];
  const float* W = (const float*)d_in[1];
  const float* b = (const float*)d_in[2];
  const float* c = (const float*)d_in[3];
  const float* d = (const float*)d_in[4];
  float* out = (float*)d_out;
  const int H = in_sizes[2];          // 1024
  const int M = in_sizes[0] / H;      // 16384

  // Scalar RK4 factor: y_final = S * z (ODE linear in y, y0 = 0).
  const int NT = 100;
  float ts[NT];
  const float step = (float)(1.0 / 99.0);
  for (int i = 0; i < NT; ++i) ts[i] = (float)i * step;
  ts[NT - 1] = 1.0f;
  double yy = 0.0;
  for (int i = 0; i < NT - 1; ++i) {
    const double t = (double)ts[i], dt = (double)(ts[i + 1] - ts[i]);
    const double k1 = t - yy;
    const double k2 = (t + 0.5 * dt) - (yy + 0.5 * dt * k1);
    const double k3 = (t + 0.5 * dt) - (yy + 0.5 * dt * k2);
    const double k4 = (t + dt) - (yy + dt * k3);
    yy += dt / 6.0 * (k1 + 2.0 * k2 + 2.0 * k3 + k4);
  }
  const float S = (float)yy;

  unsigned short* Wt = (unsigned short*)d_ws;                 // 2 MB bf16 W^T
  dim3 tgrid(H / 64, H / 64);
  transpose_W<<<tgrid, 256, 0, stream>>>(W, Wt, H);

  const size_t need = (size_t)H * H * 2 + (size_t)M * H * 2;  // Wt + x_bf16
  dim3 ggrid(H / BN, M / BM);                                 // x-fast over N tiles

  if (ws_size >= need) {
    unsigned short* xb = Wt + (size_t)H * H;                  // 32 MB bf16 x
    cvt_x<<<2048, 256, 0, stream>>>(x, xb, M * H / 4);
    gemm_fused<true><<<ggrid, 256, 0, stream>>>(x, xb, Wt, b, c, d, out, S, H);
  } else {
    gemm_fused<false><<<ggrid, 256, 0, stream>>>(x, nullptr, Wt, b, c, d, out, S, H);
  }
}